// Round 1
// baseline (349.438 us; speedup 1.0000x reference)
//
#include <hip/hip_runtime.h>
#include <math.h>

// ---------------- device helpers ----------------

__device__ __forceinline__ float srgb_to_linear(float x) {
    x = fminf(fmaxf(x, 0.0f), 1.0f);
    return (x <= 0.04045f) ? x * (1.0f / 12.92f)
                           : powf((x + 0.055f) * (1.0f / 1.055f), 2.4f);
}

__device__ __forceinline__ void oklab_ab(float r, float g, float b,
                                         float& A, float& Bc) {
    r = srgb_to_linear(r);
    g = srgb_to_linear(g);
    b = srgb_to_linear(b);
    float l = 0.4122214708f * r + 0.5363325363f * g + 0.0514459929f * b;
    float m = 0.2119034982f * r + 0.6806995451f * g + 0.1073969566f * b;
    float s = 0.0883024619f * r + 0.2817188376f * g + 0.6299787005f * b;
    l = cbrtf(fmaxf(l, 1e-10f));
    m = cbrtf(fmaxf(m, 1e-10f));
    s = cbrtf(fmaxf(s, 1e-10f));
    A  = 1.9779984951f * l - 2.428592205f * m + 0.4505937099f * s;
    Bc = 0.0259040371f * l + 0.7827717662f * m - 0.808675766f  * s;
}

// edge_soft at (y,x) for one batch (tb points at the 3-plane batch base).
__device__ __forceinline__ float edge_soft_at(const float* __restrict__ tb,
                                              int y, int x, int H, int W) {
    float best = 0.0f;
    int ym = y - 1, yp = y + 1, xm = x - 1, xp = x + 1;
    bool ymv = (ym >= 0), ypv = (yp < H), xmv = (xm >= 0), xpv = (xp < W);
#pragma unroll
    for (int c = 0; c < 3; ++c) {
        const float* p = tb + (size_t)c * H * W;
        float a00 = (ymv && xmv) ? p[ym * W + xm] : 0.0f;
        float a01 = ymv          ? p[ym * W + x ] : 0.0f;
        float a02 = (ymv && xpv) ? p[ym * W + xp] : 0.0f;
        float a10 = xmv          ? p[y  * W + xm] : 0.0f;
        float a12 = xpv          ? p[y  * W + xp] : 0.0f;
        float a20 = (ypv && xmv) ? p[yp * W + xm] : 0.0f;
        float a21 = ypv          ? p[yp * W + x ] : 0.0f;
        float a22 = (ypv && xpv) ? p[yp * W + xp] : 0.0f;
        float gx = (a02 - a00) + 2.0f * (a12 - a10) + (a22 - a20);
        float gy = (a20 - a00) + 2.0f * (a21 - a01) + (a22 - a02);
        best = fmaxf(best, fabsf(gx) + fabsf(gy));
    }
    return fminf(best * 2.0f, 1.0f);  // clip(edge/0.5, 0, 1); edge >= 0
}

// ---------------- kernels ----------------

__global__ void edge_kernel(const float* __restrict__ target,
                            float* __restrict__ edge,
                            int B, int H, int W) {
    int idx = blockIdx.x * blockDim.x + threadIdx.x;
    int total = B * H * W;
    if (idx >= total) return;
    int x = idx % W;
    int y = (idx / W) % H;
    int b = idx / (W * H);
    edge[idx] = edge_soft_at(target + (size_t)b * 3 * H * W, y, x, H, W);
}

template <int R, bool ISMAX>
__global__ void hpool(const float* __restrict__ in, float* __restrict__ out,
                      int B, int H, int W) {
    int idx = blockIdx.x * blockDim.x + threadIdx.x;
    int total = B * H * W;
    if (idx >= total) return;
    int x = idx % W;
    int rowbase = idx - x;
    int lo = max(x - R, 0), hi = min(x + R, W - 1);
    float v = in[rowbase + lo];
    for (int xx = lo + 1; xx <= hi; ++xx) {
        float u = in[rowbase + xx];
        v = ISMAX ? fmaxf(v, u) : fminf(v, u);
    }
    out[idx] = v;
}

template <int R, bool ISMAX>
__global__ void vpool(const float* __restrict__ in, float* __restrict__ out,
                      int B, int H, int W) {
    int idx = blockIdx.x * blockDim.x + threadIdx.x;
    int total = B * H * W;
    if (idx >= total) return;
    int y = (idx / W) % H;
    int colbase = idx - y * W;  // b*H*W + x
    int lo = max(y - R, 0), hi = min(y + R, H - 1);
    float v = in[colbase + lo * W];
    for (int yy = lo + 1; yy <= hi; ++yy) {
        float u = in[colbase + yy * W];
        v = ISMAX ? fmaxf(v, u) : fminf(v, u);
    }
    out[idx] = v;
}

// vertical min pool + relu(closed - edge_soft), edge from buffer
template <int R>
__global__ void vmin_sub_relu(const float* __restrict__ in,
                              const float* __restrict__ edge,
                              float* __restrict__ out,
                              int B, int H, int W) {
    int idx = blockIdx.x * blockDim.x + threadIdx.x;
    int total = B * H * W;
    if (idx >= total) return;
    int y = (idx / W) % H;
    int colbase = idx - y * W;
    int lo = max(y - R, 0), hi = min(y + R, H - 1);
    float v = in[colbase + lo * W];
    for (int yy = lo + 1; yy <= hi; ++yy) v = fminf(v, in[colbase + yy * W]);
    out[idx] = fmaxf(v - edge[idx], 0.0f);
}

// vertical min pool + relu(closed - edge_soft), edge recomputed from target
template <int R>
__global__ void vmin_sub_recomp(const float* __restrict__ in,
                                const float* __restrict__ target,
                                float* __restrict__ out,
                                int B, int H, int W) {
    int idx = blockIdx.x * blockDim.x + threadIdx.x;
    int total = B * H * W;
    if (idx >= total) return;
    int x = idx % W;
    int y = (idx / W) % H;
    int b = idx / (W * H);
    int colbase = idx - y * W;
    int lo = max(y - R, 0), hi = min(y + R, H - 1);
    float v = in[colbase + lo * W];
    for (int yy = lo + 1; yy <= hi; ++yy) v = fminf(v, in[colbase + yy * W]);
    float es = edge_soft_at(target + (size_t)b * 3 * H * W, y, x, H, W);
    out[idx] = fmaxf(v - es, 0.0f);
}

__global__ void loss_kernel(const float* __restrict__ pred,
                            const float* __restrict__ target,
                            const float* __restrict__ mask,
                            float* __restrict__ partials,
                            int B, int HWp, int nb) {
    int total = B * HWp;
    float sm = 0.0f, sc = 0.0f, sh = 0.0f;
    for (int idx = blockIdx.x * blockDim.x + threadIdx.x; idx < total;
         idx += gridDim.x * blockDim.x) {
        float m = mask[idx];
        sm += m;
        if (m > 0.0f) {  // whole wave skips via execz when all lanes masked out
            int b = idx / HWp;
            int q = idx - b * HWp;
            size_t off = (size_t)b * 3 * HWp + q;
            float pa, pb, ta, tb;
            oklab_ab(pred[off], pred[off + HWp], pred[off + 2 * HWp], pa, pb);
            oklab_ab(target[off], target[off + HWp], target[off + 2 * HWp], ta, tb);
            float Cp = sqrtf(pa * pa + pb * pb + 1e-12f);
            float Cg = sqrtf(ta * ta + tb * tb + 1e-12f);
            sc += fabsf(Cp - Cg) * m;
            float cosd = (pa * ta + pb * tb) / (Cp * Cg + 1e-12f);
            cosd = fminf(fmaxf(cosd, -1.0f), 1.0f);
            sh += fmaxf(Cg, 0.01f) * (1.0f - cosd) * m;
        }
    }
    // wave reduce (64 lanes)
#pragma unroll
    for (int off = 32; off > 0; off >>= 1) {
        sm += __shfl_down(sm, off);
        sc += __shfl_down(sc, off);
        sh += __shfl_down(sh, off);
    }
    __shared__ float smem[3][8];
    int lane = threadIdx.x & 63;
    int wav  = threadIdx.x >> 6;
    if (lane == 0) { smem[0][wav] = sm; smem[1][wav] = sc; smem[2][wav] = sh; }
    __syncthreads();
    if (threadIdx.x == 0) {
        float tm = 0, tc = 0, th = 0;
        int nw = blockDim.x >> 6;
        for (int i = 0; i < nw; ++i) {
            tm += smem[0][i]; tc += smem[1][i]; th += smem[2][i];
        }
        partials[blockIdx.x]          = tm;
        partials[nb + blockIdx.x]     = tc;
        partials[2 * nb + blockIdx.x] = th;
    }
}

__global__ void finalize_kernel(const float* __restrict__ partials, int nb,
                                float* __restrict__ out) {
    double sm = 0.0, sc = 0.0, sh = 0.0;
    for (int i = threadIdx.x; i < nb; i += blockDim.x) {
        sm += (double)partials[i];
        sc += (double)partials[nb + i];
        sh += (double)partials[2 * nb + i];
    }
    __shared__ double red[3][256];
    red[0][threadIdx.x] = sm;
    red[1][threadIdx.x] = sc;
    red[2][threadIdx.x] = sh;
    __syncthreads();
    for (int s = blockDim.x / 2; s > 0; s >>= 1) {
        if ((int)threadIdx.x < s) {
            red[0][threadIdx.x] += red[0][threadIdx.x + s];
            red[1][threadIdx.x] += red[1][threadIdx.x + s];
            red[2][threadIdx.x] += red[2][threadIdx.x + s];
        }
        __syncthreads();
    }
    if (threadIdx.x == 0) {
        double ms = fmax(red[0][0], 1.0);
        out[0] = (float)(red[1][0] / ms + 2.0 * red[2][0] / ms);
    }
}

// ---------------- host launch ----------------

extern "C" void kernel_launch(void* const* d_in, const int* in_sizes, int n_in,
                              void* d_out, int out_size, void* d_ws, size_t ws_size,
                              hipStream_t stream) {
    const float* pred   = (const float*)d_in[0];
    const float* target = (const float*)d_in[1];
    float* out = (float*)d_out;

    const int H = 1024, W = 1024;
    int Bn = in_sizes[0] / (3 * H * W);
    int HWp = H * W;
    int total = Bn * HWp;
    size_t plane = (size_t)total * sizeof(float);

    const int NT = 256;
    const int NB = 2048;  // loss-kernel grid (grid-stride)
    int blocks = (total + NT - 1) / NT;

    char* ws = (char*)d_ws;
    float* A  = (float*)ws;
    float* Bb = (float*)(ws + plane);
    size_t part_bytes = (size_t)3 * NB * sizeof(float);
    bool three = ws_size >= 3 * plane + part_bytes + 256;
    float* Cc = three ? (float*)(ws + 2 * plane) : nullptr;
    float* partials = (float*)(ws + (three ? 3 : 2) * plane);

    // 1. edge_soft(target) -> A
    edge_kernel<<<blocks, NT, 0, stream>>>(target, A, Bn, H, W);
    // 2. horizontal max 11 -> B
    hpool<5, true><<<blocks, NT, 0, stream>>>(A, Bb, Bn, H, W);

    if (three) {
        // 3. vertical max 11 -> C (dilated)
        vpool<5, true><<<blocks, NT, 0, stream>>>(Bb, Cc, Bn, H, W);
        // 4. horizontal min 11 -> B
        hpool<5, false><<<blocks, NT, 0, stream>>>(Cc, Bb, Bn, H, W);
        // 5. vertical min 11 + relu(closed - edge) -> C (mask0)
        vmin_sub_relu<5><<<blocks, NT, 0, stream>>>(Bb, A, Cc, Bn, H, W);
        // 6. horizontal max 5 -> B
        hpool<2, true><<<blocks, NT, 0, stream>>>(Cc, Bb, Bn, H, W);
        // 7. vertical max 5 -> A (final mask)
        vpool<2, true><<<blocks, NT, 0, stream>>>(Bb, A, Bn, H, W);
    } else {
        // 2-buffer fallback: recompute edge_soft in step 5
        vpool<5, true><<<blocks, NT, 0, stream>>>(Bb, A, Bn, H, W);   // dilated -> A
        hpool<5, false><<<blocks, NT, 0, stream>>>(A, Bb, Bn, H, W);  // hmin -> B
        vmin_sub_recomp<5><<<blocks, NT, 0, stream>>>(Bb, target, A, Bn, H, W); // mask0 -> A
        hpool<2, true><<<blocks, NT, 0, stream>>>(A, Bb, Bn, H, W);   // -> B
        vpool<2, true><<<blocks, NT, 0, stream>>>(Bb, A, Bn, H, W);   // mask -> A
    }

    // 8. masked color loss -> per-block partials
    loss_kernel<<<NB, NT, 0, stream>>>(pred, target, A, partials, Bn, HWp, NB);
    // 9. final reduce + combine
    finalize_kernel<<<1, 256, 0, stream>>>(partials, NB, out);
}

// Round 2
// 234.017 us; speedup vs baseline: 1.4932x; 1.4932x over previous
//
#include <hip/hip_runtime.h>
#include <math.h>

#define TS 64          // output tile
#define EH 74          // edge region: rel [-5, 69)
#define TH 76          // target stage: rel [-6, 70)
#define DH 74          // dilated stage: rel [-5, 69)
#define MH 68          // mask0 stage: rel [-2, 66)

// ---------------- device helpers ----------------

__device__ __forceinline__ float srgb_to_linear(float x) {
    x = fminf(fmaxf(x, 0.0f), 1.0f);
    return (x <= 0.04045f) ? x * (1.0f / 12.92f)
                           : powf((x + 0.055f) * (1.0f / 1.055f), 2.4f);
}

__device__ __forceinline__ void oklab_ab(float r, float g, float b,
                                         float& A, float& Bc) {
    r = srgb_to_linear(r);
    g = srgb_to_linear(g);
    b = srgb_to_linear(b);
    float l = 0.4122214708f * r + 0.5363325363f * g + 0.0514459929f * b;
    float m = 0.2119034982f * r + 0.6806995451f * g + 0.1073969566f * b;
    float s = 0.0883024619f * r + 0.2817188376f * g + 0.6299787005f * b;
    l = cbrtf(fmaxf(l, 1e-10f));
    m = cbrtf(fmaxf(m, 1e-10f));
    s = cbrtf(fmaxf(s, 1e-10f));
    A  = 1.9779984951f * l - 2.428592205f * m + 0.4505937099f * s;
    Bc = 0.0259040371f * l + 0.7827717662f * m - 0.808675766f  * s;
}

__device__ __forceinline__ void decode_tile(int blk, int H, int W,
                                            int& b, int& ty, int& tx) {
    int tpr = W / TS;
    int tpi = (H / TS) * tpr;
    b = blk / tpi;
    int t = blk % tpi;
    ty = (t / tpr) * TS;
    tx = (t % tpr) * TS;
}

// ---------------- K12: edge_soft + 11x11 max-pool (fused, tiled) ----------------
// writes edge plane and dilated plane.

__global__ __launch_bounds__(256) void k12_edge_dilate(
    const float* __restrict__ target, float* __restrict__ edge,
    float* __restrict__ dil, int H, int W) {
    __shared__ float s_tgt[TH * TH];   // reused as s_tmp after edge is built
    __shared__ float s_E[EH * EH];
    float* s_tmp = s_tgt;              // 74*64 <= 76*76

    int b, ty, tx;
    decode_tile(blockIdx.x, H, W, b, ty, tx);
    const float* tb = target + (size_t)b * 3 * H * W;
    int tid = threadIdx.x;

    for (int i = tid; i < EH * EH; i += 256) s_E[i] = 0.0f;

    for (int c = 0; c < 3; ++c) {
        const float* p = tb + (size_t)c * H * W;
        __syncthreads();
        // stage channel c: rel [-6,70)^2, ZERO outside image (sobel zero-pad)
        for (int i = tid; i < TH * TH; i += 256) {
            int r = i / TH - 6 + ty;
            int q = i % TH - 6 + tx;
            s_tgt[i] = (r >= 0 && r < H && q >= 0 && q < W)
                           ? p[(size_t)r * W + q] : 0.0f;
        }
        __syncthreads();
        // sobel grad at E slots rel [-5,69); out-of-image slots computed at
        // clamped coords (replicate ≡ clamped pooling window).
        for (int i = tid; i < EH * EH; i += 256) {
            int r = i / EH - 5 + ty;
            int q = i % EH - 5 + tx;
            r = min(max(r, 0), H - 1);
            q = min(max(q, 0), W - 1);
            int lr = r - ty + 6, lq = q - tx + 6;
            const float* s0 = s_tgt + (lr - 1) * TH + lq;
            const float* s1 = s_tgt + lr * TH + lq;
            const float* s2 = s_tgt + (lr + 1) * TH + lq;
            float a00 = s0[-1], a01 = s0[0], a02 = s0[1];
            float a10 = s1[-1],              a12 = s1[1];
            float a20 = s2[-1], a21 = s2[0], a22 = s2[1];
            float gx = (a02 - a00) + 2.0f * (a12 - a10) + (a22 - a20);
            float gy = (a20 - a00) + 2.0f * (a21 - a01) + (a22 - a02);
            s_E[i] = fmaxf(s_E[i], fabsf(gx) + fabsf(gy));
        }
    }
    __syncthreads();
    // edge_soft = clip(edge/0.5, 0, 1) = min(2*edge, 1)
    for (int i = tid; i < EH * EH; i += 256)
        s_E[i] = fminf(2.0f * s_E[i], 1.0f);
    __syncthreads();
    // horizontal max-11 -> tmp[EH][TS]
    for (int i = tid; i < EH * TS; i += 256) {
        int r = i / TS, x = i % TS;
        const float* row = s_E + r * EH + x;  // cols x..x+10 == rel x-5..x+5
        float v = row[0];
#pragma unroll
        for (int k = 1; k < 11; ++k) v = fmaxf(v, row[k]);
        s_tmp[r * TS + x] = v;
    }
    __syncthreads();
    // vertical max-11 + write edge & dilated
    for (int i = tid; i < TS * TS; i += 256) {
        int y = i / TS, x = i % TS;
        float v = s_tmp[y * TS + x];
#pragma unroll
        for (int k = 1; k < 11; ++k) v = fmaxf(v, s_tmp[(y + k) * TS + x]);
        size_t gi = (size_t)b * H * W + (size_t)(ty + y) * W + (tx + x);
        dil[gi]  = v;
        edge[gi] = s_E[(y + 5) * EH + (x + 5)];
    }
}

// ---------------- K3: 11x11 min-pool + relu(closed - edge) ----------------
// planeA holds edge on entry; each block reads edge only at its own tile,
// then overwrites the same addresses with mask0 (thread-local read-then-write).

__global__ __launch_bounds__(256) void k3_close_mask(
    const float* __restrict__ dil, float* __restrict__ edge_mask,
    int H, int W) {
    __shared__ float s_d[DH * DH];
    __shared__ float s_tmp[DH * TS];

    int b, ty, tx;
    decode_tile(blockIdx.x, H, W, b, ty, tx);
    int tid = threadIdx.x;
    size_t base = (size_t)b * H * W;

    // stage dilated rel [-5,69), replicate-clamp (== clamped window for min)
    for (int i = tid; i < DH * DH; i += 256) {
        int r = min(max(i / DH - 5 + ty, 0), H - 1);
        int q = min(max(i % DH - 5 + tx, 0), W - 1);
        s_d[i] = dil[base + (size_t)r * W + q];
    }
    __syncthreads();
    // horizontal min-11
    for (int i = tid; i < DH * TS; i += 256) {
        int r = i / TS, x = i % TS;
        const float* row = s_d + r * DH + x;
        float v = row[0];
#pragma unroll
        for (int k = 1; k < 11; ++k) v = fminf(v, row[k]);
        s_tmp[r * TS + x] = v;
    }
    __syncthreads();
    // vertical min-11 + subtract edge + relu
    for (int i = tid; i < TS * TS; i += 256) {
        int y = i / TS, x = i % TS;
        float v = s_tmp[y * TS + x];
#pragma unroll
        for (int k = 1; k < 11; ++k) v = fminf(v, s_tmp[(y + k) * TS + x]);
        size_t gi = base + (size_t)(ty + y) * W + (tx + x);
        edge_mask[gi] = fmaxf(v - edge_mask[gi], 0.0f);
    }
}

// ---------------- K4: 5x5 max-pool + masked OKLab loss ----------------

__global__ __launch_bounds__(256) void k4_loss(
    const float* __restrict__ pred, const float* __restrict__ target,
    const float* __restrict__ mask0, float* __restrict__ partials,
    int H, int W, int nb) {
    __shared__ float s_m[MH * MH];
    __shared__ float s_tmp[MH * TS];
    __shared__ float s_red[3][4];

    int b, ty, tx;
    decode_tile(blockIdx.x, H, W, b, ty, tx);
    int tid = threadIdx.x;
    size_t base = (size_t)b * H * W;
    size_t cbase = (size_t)b * 3 * H * W;
    int HWp = H * W;

    // stage mask0 rel [-2,66), replicate-clamp
    for (int i = tid; i < MH * MH; i += 256) {
        int r = min(max(i / MH - 2 + ty, 0), H - 1);
        int q = min(max(i % MH - 2 + tx, 0), W - 1);
        s_m[i] = mask0[base + (size_t)r * W + q];
    }
    __syncthreads();
    // horizontal max-5
    for (int i = tid; i < MH * TS; i += 256) {
        int r = i / TS, x = i % TS;
        const float* row = s_m + r * MH + x;
        float v = row[0];
#pragma unroll
        for (int k = 1; k < 5; ++k) v = fmaxf(v, row[k]);
        s_tmp[r * TS + x] = v;
    }
    __syncthreads();

    float sm = 0.0f, sc = 0.0f, sh = 0.0f;
    // vertical max-5 + masked loss
    for (int i = tid; i < TS * TS; i += 256) {
        int y = i / TS, x = i % TS;
        float m = s_tmp[y * TS + x];
#pragma unroll
        for (int k = 1; k < 5; ++k) m = fmaxf(m, s_tmp[(y + k) * TS + x]);
        sm += m;
        if (m > 0.0f) {
            size_t off = cbase + (size_t)(ty + y) * W + (tx + x);
            float pa, pb, ta, tb;
            oklab_ab(pred[off], pred[off + HWp], pred[off + 2 * HWp], pa, pb);
            oklab_ab(target[off], target[off + HWp], target[off + 2 * HWp], ta, tb);
            float Cp = sqrtf(pa * pa + pb * pb + 1e-12f);
            float Cg = sqrtf(ta * ta + tb * tb + 1e-12f);
            sc += fabsf(Cp - Cg) * m;
            float cosd = (pa * ta + pb * tb) / (Cp * Cg + 1e-12f);
            cosd = fminf(fmaxf(cosd, -1.0f), 1.0f);
            sh += fmaxf(Cg, 0.01f) * (1.0f - cosd) * m;
        }
    }
    // wave reduce (64 lanes)
#pragma unroll
    for (int off = 32; off > 0; off >>= 1) {
        sm += __shfl_down(sm, off);
        sc += __shfl_down(sc, off);
        sh += __shfl_down(sh, off);
    }
    int lane = threadIdx.x & 63;
    int wav  = threadIdx.x >> 6;
    if (lane == 0) { s_red[0][wav] = sm; s_red[1][wav] = sc; s_red[2][wav] = sh; }
    __syncthreads();
    if (threadIdx.x == 0) {
        float tm = 0, tc = 0, th = 0;
        for (int i = 0; i < 4; ++i) {
            tm += s_red[0][i]; tc += s_red[1][i]; th += s_red[2][i];
        }
        partials[blockIdx.x]          = tm;
        partials[nb + blockIdx.x]     = tc;
        partials[2 * nb + blockIdx.x] = th;
    }
}

__global__ void finalize_kernel(const float* __restrict__ partials, int nb,
                                float* __restrict__ out) {
    double sm = 0.0, sc = 0.0, sh = 0.0;
    for (int i = threadIdx.x; i < nb; i += blockDim.x) {
        sm += (double)partials[i];
        sc += (double)partials[nb + i];
        sh += (double)partials[2 * nb + i];
    }
    __shared__ double red[3][256];
    red[0][threadIdx.x] = sm;
    red[1][threadIdx.x] = sc;
    red[2][threadIdx.x] = sh;
    __syncthreads();
    for (int s = blockDim.x / 2; s > 0; s >>= 1) {
        if ((int)threadIdx.x < s) {
            red[0][threadIdx.x] += red[0][threadIdx.x + s];
            red[1][threadIdx.x] += red[1][threadIdx.x + s];
            red[2][threadIdx.x] += red[2][threadIdx.x + s];
        }
        __syncthreads();
    }
    if (threadIdx.x == 0) {
        double ms = fmax(red[0][0], 1.0);
        out[0] = (float)(red[1][0] / ms + 2.0 * red[2][0] / ms);
    }
}

// ---------------- host launch ----------------

extern "C" void kernel_launch(void* const* d_in, const int* in_sizes, int n_in,
                              void* d_out, int out_size, void* d_ws, size_t ws_size,
                              hipStream_t stream) {
    const float* pred   = (const float*)d_in[0];
    const float* target = (const float*)d_in[1];
    float* out = (float*)d_out;

    const int H = 1024, W = 1024;
    int Bn = in_sizes[0] / (3 * H * W);
    size_t plane = (size_t)Bn * H * W * sizeof(float);

    int nblk = Bn * (H / TS) * (W / TS);  // 2048 for B=8

    char* ws = (char*)d_ws;
    float* planeA = (float*)ws;                 // edge, then mask0 (in place)
    float* planeB = (float*)(ws + plane);       // dilated
    float* partials = (float*)(ws + 2 * plane); // 3 * nblk floats

    k12_edge_dilate<<<nblk, 256, 0, stream>>>(target, planeA, planeB, H, W);
    k3_close_mask<<<nblk, 256, 0, stream>>>(planeB, planeA, H, W);
    k4_loss<<<nblk, 256, 0, stream>>>(pred, target, planeA, partials, H, W, nblk);
    finalize_kernel<<<1, 256, 0, stream>>>(partials, nblk, out);
}

// Round 3
// 109.670 us; speedup vs baseline: 3.1863x; 2.1338x over previous
//
#include <hip/hip_runtime.h>
#include <math.h>

#define SROWS 64   // rows per block strip
#define PCH   16   // rows per LDS phase
#define QCAP  1024 // k4 compaction queue entries

// ---------------- device helpers ----------------

__device__ __forceinline__ float srgb_to_linear(float x) {
    x = fminf(fmaxf(x, 0.0f), 1.0f);
    return (x <= 0.04045f) ? x * (1.0f / 12.92f)
                           : powf((x + 0.055f) * (1.0f / 1.055f), 2.4f);
}

__device__ __forceinline__ void oklab_ab(float r, float g, float b,
                                         float& A, float& Bc) {
    r = srgb_to_linear(r);
    g = srgb_to_linear(g);
    b = srgb_to_linear(b);
    float l = 0.4122214708f * r + 0.5363325363f * g + 0.0514459929f * b;
    float m = 0.2119034982f * r + 0.6806995451f * g + 0.1073969566f * b;
    float s = 0.0883024619f * r + 0.2817188376f * g + 0.6299787005f * b;
    l = cbrtf(fmaxf(l, 1e-10f));
    m = cbrtf(fmaxf(m, 1e-10f));
    s = cbrtf(fmaxf(s, 1e-10f));
    A  = 1.9779984951f * l - 2.428592205f * m + 0.4505937099f * s;
    Bc = 0.0259040371f * l + 0.7827717662f * m - 0.808675766f  * s;
}

__device__ __forceinline__ void color_terms(const float* __restrict__ pred,
                                            const float* __restrict__ target,
                                            size_t off, size_t HWp, float m,
                                            float& sc, float& sh) {
    float pa, pb, ta, tb;
    oklab_ab(pred[off], pred[off + HWp], pred[off + 2 * HWp], pa, pb);
    oklab_ab(target[off], target[off + HWp], target[off + 2 * HWp], ta, tb);
    float Cp = sqrtf(pa * pa + pb * pb + 1e-12f);
    float Cg = sqrtf(ta * ta + tb * tb + 1e-12f);
    sc += fabsf(Cp - Cg) * m;
    float cosd = (pa * ta + pb * tb) / (Cp * Cg + 1e-12f);
    cosd = fminf(fmaxf(cosd, -1.0f), 1.0f);
    sh += fmaxf(Cg, 0.01f) * (1.0f - cosd) * m;
}

// ---------------- K1: sobel edge_soft (zero-pad), register+shuffle ----------------
// Each wave covers 62 output columns (lanes 0 and 63 are halo). No LDS.

__global__ __launch_bounds__(256) void k1_edge(const float* __restrict__ target,
                                               float* __restrict__ edge,
                                               int H, int W) {
    const int WC = 62, BC = 248;  // cols per wave / per block
    int cb = (W + BC - 1) / BC;
    int rs = H / SROWS;
    int blk = blockIdx.x;
    int b   = blk / (cb * rs);
    int t   = blk % (cb * rs);
    int bxi = t / rs, ysi = t % rs;
    int lane = threadIdx.x & 63, wid = threadIdx.x >> 6;
    int c  = bxi * BC + wid * WC + lane - 1;
    int y0 = ysi * SROWS;
    size_t plane = (size_t)H * W;
    const float* tb = target + (size_t)b * 3 * plane;
    bool inc = (c >= 0 && c < W);
    bool store_ok = (lane >= 1 && lane <= WC && c < W);
    float* ep = edge + (size_t)b * plane + c;
    int lp = min(lane + 1, 63), lm = max(lane - 1, 0);

    float pr0, pr1, pr2, cu0, cu1, cu2;
    {
        bool ok = inc && (y0 - 1 >= 0);
        const float* p = tb + (size_t)(y0 - 1) * W + c;
        pr0 = ok ? p[0] : 0.f; pr1 = ok ? p[plane] : 0.f; pr2 = ok ? p[2 * plane] : 0.f;
    }
    {
        const float* p = tb + (size_t)y0 * W + c;
        cu0 = inc ? p[0] : 0.f; cu1 = inc ? p[plane] : 0.f; cu2 = inc ? p[2 * plane] : 0.f;
    }
#pragma unroll 2
    for (int y = y0; y < y0 + SROWS; ++y) {
        bool ok = inc && (y + 1 < H);
        const float* p = tb + (size_t)(y + 1) * W + c;
        float nx0 = ok ? p[0] : 0.f;
        float nx1 = ok ? p[plane] : 0.f;
        float nx2 = ok ? p[2 * plane] : 0.f;
        float g = 0.f;
#define SOBEL_CH(PR, CU, NX)                                              \
        {                                                                 \
            float u = PR + 2.f * CU + NX;                                 \
            float v = NX - PR;                                            \
            float up = __shfl(u, lp), um = __shfl(u, lm);                 \
            float vp = __shfl(v, lp), vm = __shfl(v, lm);                 \
            g = fmaxf(g, fabsf(up - um) + fabsf(vm + 2.f * v + vp));      \
        }
        SOBEL_CH(pr0, cu0, nx0)
        SOBEL_CH(pr1, cu1, nx1)
        SOBEL_CH(pr2, cu2, nx2)
#undef SOBEL_CH
        if (store_ok) ep[(size_t)y * W] = fminf(2.f * g, 1.f);
        pr0 = cu0; pr1 = cu1; pr2 = cu2;
        cu0 = nx0; cu1 = nx1; cu2 = nx2;
    }
}

// ---------------- column-strip 2-D pool (vertical in regs, horizontal via LDS) ----

template <int R, bool ISMAX, bool SUB_EDGE>
__global__ __launch_bounds__(256) void pool_kernel(const float* __restrict__ in,
                                                   const float* __restrict__ edge,
                                                   float* __restrict__ out,
                                                   int H, int W) {
    const int OUTW = 256 - 2 * R;
    __shared__ float s_v[PCH][256];
    int cb = (W + OUTW - 1) / OUTW;
    int rs = H / SROWS;
    int blk = blockIdx.x;
    int b   = blk / (cb * rs);
    int t   = blk % (cb * rs);
    int bxi = t / rs, ysi = t % rs;
    int tid = threadIdx.x;
    int col = bxi * OUTW - R + tid;
    int cc  = min(max(col, 0), W - 1);  // replicate == clamped window
    size_t base = (size_t)b * H * W;
    const float* colp = in + base + cc;
    int ys = ysi * SROWS;
    bool writer = (tid >= R) && (tid < OUTW + R) && (col < W);

    for (int ph = 0; ph < SROWS / PCH; ++ph) {
        int y0 = ys + ph * PCH;
        float w[PCH + 2 * R];
#pragma unroll
        for (int k = 0; k < PCH + 2 * R; ++k) {
            int r = min(max(y0 - R + k, 0), H - 1);
            w[k] = colp[(size_t)r * W];
        }
        float v[PCH];
#pragma unroll
        for (int k = 0; k < PCH; ++k) {
            float m = w[k];
#pragma unroll
            for (int d = 1; d <= 2 * R; ++d)
                m = ISMAX ? fmaxf(m, w[k + d]) : fminf(m, w[k + d]);
            v[k] = m;
        }
        __syncthreads();  // previous phase's readers done
#pragma unroll
        for (int k = 0; k < PCH; ++k) s_v[k][tid] = v[k];
        __syncthreads();
        if (writer) {
#pragma unroll
            for (int k = 0; k < PCH; ++k) {
                float m = s_v[k][tid - R];
#pragma unroll
                for (int d = 1; d <= 2 * R; ++d)
                    m = ISMAX ? fmaxf(m, s_v[k][tid - R + d])
                              : fminf(m, s_v[k][tid - R + d]);
                size_t gi = base + (size_t)(y0 + k) * W + col;
                out[gi] = SUB_EDGE ? fmaxf(m - edge[gi], 0.f) : m;
            }
        }
    }
}

// ---------------- K4: 5x5 max-pool + compacted masked OKLab loss ----------------

__global__ __launch_bounds__(256) void k4_loss(const float* __restrict__ pred,
                                               const float* __restrict__ target,
                                               const float* __restrict__ mask0,
                                               float* __restrict__ partials,
                                               int H, int W, int nb) {
    const int R = 2, OUTW = 256 - 2 * R;
    __shared__ float s_v[PCH][256];
    __shared__ int   q_pos[QCAP];
    __shared__ float q_m[QCAP];
    __shared__ int   cnt;
    __shared__ float s_red[3][4];

    int cb = (W + OUTW - 1) / OUTW;
    int rs = H / SROWS;
    int blk = blockIdx.x;
    int b   = blk / (cb * rs);
    int t   = blk % (cb * rs);
    int bxi = t / rs, ysi = t % rs;
    int tid = threadIdx.x;
    int col = bxi * OUTW - R + tid;
    int cc  = min(max(col, 0), W - 1);
    size_t HWp  = (size_t)H * W;
    size_t base = (size_t)b * HWp;
    size_t cbase = (size_t)b * 3 * HWp;
    const float* colp = mask0 + base + cc;
    int ys = ysi * SROWS;
    bool writer = (tid >= R) && (tid < OUTW + R) && (col < W);

    float sm = 0.f, sc = 0.f, sh = 0.f;

    for (int ph = 0; ph < SROWS / PCH; ++ph) {
        int y0 = ys + ph * PCH;
        float w[PCH + 2 * R];
#pragma unroll
        for (int k = 0; k < PCH + 2 * R; ++k) {
            int r = min(max(y0 - R + k, 0), H - 1);
            w[k] = colp[(size_t)r * W];
        }
        float v[PCH];
#pragma unroll
        for (int k = 0; k < PCH; ++k) {
            float m = w[k];
#pragma unroll
            for (int d = 1; d <= 2 * R; ++d) m = fmaxf(m, w[k + d]);
            v[k] = m;
        }
        __syncthreads();  // prev phase queue-processing done
#pragma unroll
        for (int k = 0; k < PCH; ++k) s_v[k][tid] = v[k];
        if (tid == 0) cnt = 0;
        __syncthreads();
        if (writer) {
#pragma unroll
            for (int k = 0; k < PCH; ++k) {
                float m = s_v[k][tid - R];
#pragma unroll
                for (int d = 1; d <= 2 * R; ++d)
                    m = fmaxf(m, s_v[k][tid - R + d]);
                sm += m;
                if (m > 0.f) {
                    int pos = atomicAdd(&cnt, 1);
                    if (pos < QCAP) {
                        q_pos[pos] = ((y0 + k) << 16) | col;
                        q_m[pos] = m;
                    } else {  // overflow fallback (dense mask) — compute inline
                        color_terms(pred, target,
                                    cbase + (size_t)(y0 + k) * W + col,
                                    HWp, m, sc, sh);
                    }
                }
            }
        }
        __syncthreads();
        int n = min(cnt, QCAP);
        for (int i = tid; i < n; i += 256) {
            int pk = q_pos[i];
            color_terms(pred, target,
                        cbase + (size_t)(pk >> 16) * W + (pk & 0xffff),
                        HWp, q_m[i], sc, sh);
        }
    }

    // wave reduce (64 lanes)
#pragma unroll
    for (int off = 32; off > 0; off >>= 1) {
        sm += __shfl_down(sm, off);
        sc += __shfl_down(sc, off);
        sh += __shfl_down(sh, off);
    }
    int lane = tid & 63, wav = tid >> 6;
    __syncthreads();
    if (lane == 0) { s_red[0][wav] = sm; s_red[1][wav] = sc; s_red[2][wav] = sh; }
    __syncthreads();
    if (tid == 0) {
        float tm = 0, tc = 0, th = 0;
        for (int i = 0; i < 4; ++i) {
            tm += s_red[0][i]; tc += s_red[1][i]; th += s_red[2][i];
        }
        partials[blk]          = tm;
        partials[nb + blk]     = tc;
        partials[2 * nb + blk] = th;
    }
}

__global__ void finalize_kernel(const float* __restrict__ partials, int nb,
                                float* __restrict__ out) {
    double sm = 0.0, sc = 0.0, sh = 0.0;
    for (int i = threadIdx.x; i < nb; i += blockDim.x) {
        sm += (double)partials[i];
        sc += (double)partials[nb + i];
        sh += (double)partials[2 * nb + i];
    }
    __shared__ double red[3][256];
    red[0][threadIdx.x] = sm;
    red[1][threadIdx.x] = sc;
    red[2][threadIdx.x] = sh;
    __syncthreads();
    for (int s = blockDim.x / 2; s > 0; s >>= 1) {
        if ((int)threadIdx.x < s) {
            red[0][threadIdx.x] += red[0][threadIdx.x + s];
            red[1][threadIdx.x] += red[1][threadIdx.x + s];
            red[2][threadIdx.x] += red[2][threadIdx.x + s];
        }
        __syncthreads();
    }
    if (threadIdx.x == 0) {
        double ms = fmax(red[0][0], 1.0);
        out[0] = (float)(red[1][0] / ms + 2.0 * red[2][0] / ms);
    }
}

// ---------------- host launch ----------------

extern "C" void kernel_launch(void* const* d_in, const int* in_sizes, int n_in,
                              void* d_out, int out_size, void* d_ws, size_t ws_size,
                              hipStream_t stream) {
    const float* pred   = (const float*)d_in[0];
    const float* target = (const float*)d_in[1];
    float* out = (float*)d_out;

    const int H = 1024, W = 1024;
    int Bn = in_sizes[0] / (3 * H * W);
    size_t plane = (size_t)Bn * H * W * sizeof(float);

    char* ws = (char*)d_ws;
    float* planeA = (float*)ws;            // edge, then mask0 (in place)
    float* planeB = (float*)(ws + plane);  // dilated
    float* partials = (float*)(ws + 2 * plane);

    int rs = H / SROWS;                       // 16
    int cb1 = (W + 247) / 248;                // 5
    int cbP = (W + 245) / 246;                // 5
    int cb4 = (W + 251) / 252;                // 5
    int g1 = Bn * cb1 * rs;
    int gP = Bn * cbP * rs;
    int g4 = Bn * cb4 * rs;

    // 1. sobel edge_soft -> planeA
    k1_edge<<<g1, 256, 0, stream>>>(target, planeA, H, W);
    // 2. 11x11 max-pool -> planeB (dilated)
    pool_kernel<5, true, false><<<gP, 256, 0, stream>>>(planeA, nullptr, planeB, H, W);
    // 3. 11x11 min-pool + relu(closed - edge) -> planeA in place (mask0)
    pool_kernel<5, false, true><<<gP, 256, 0, stream>>>(planeB, planeA, planeA, H, W);
    // 4. 5x5 max-pool + compacted masked loss -> partials
    k4_loss<<<g4, 256, 0, stream>>>(pred, target, planeA, partials, H, W, g4);
    // 5. final reduce + combine
    finalize_kernel<<<1, 256, 0, stream>>>(partials, g4, out);
}